// Round 10
// baseline (419.388 us; speedup 1.0000x reference)
//
#include <hip/hip_runtime.h>
#include <math.h>

#define NNODES 50000
#define NEDGES 800000
#define NGRAPH 64
#define DIM_IN 128
#define HCDIM  192
#define QKVRW  768

typedef __attribute__((ext_vector_type(8))) short short8;
typedef __attribute__((ext_vector_type(4))) float f32x4;
typedef __attribute__((ext_vector_type(2))) float f32x2;

__device__ __forceinline__ unsigned short f2bf(float f){
  unsigned int u = __float_as_uint(f);
  unsigned int r = (u + 0x7fffu + ((u>>16)&1u)) >> 16;
  return (unsigned short)r;
}

__device__ __forceinline__ f32x2 bf2_to_f2(unsigned int u){
  f32x2 r;
  r[0] = __uint_as_float(u<<16);
  r[1] = __uint_as_float(u & 0xffff0000u);
  return r;
}

__device__ __forceinline__ f32x2 fp8_lo(unsigned int u){
  return __builtin_amdgcn_cvt_pk_f32_fp8((int)u, false);
}
__device__ __forceinline__ f32x2 fp8_hi(unsigned int u){
  return __builtin_amdgcn_cvt_pk_f32_fp8((int)u, true);
}

__device__ __forceinline__ float wave_sum(float v){
#pragma unroll
  for(int off=32; off>0; off>>=1) v += __shfl_xor(v, off, 64);
  return v;
}

// ---------------- CSR scan kernels ----------------
__global__ void scan_partial(const int* __restrict__ counts, int* __restrict__ bsum, int N){
  __shared__ int lds[256];
  int t = threadIdx.x;
  int idx = blockIdx.x*256 + t;
  int v = (idx<N)? counts[idx] : 0;
  lds[t]=v; __syncthreads();
#pragma unroll
  for(int off=128; off>0; off>>=1){
    if(t<off) lds[t]+=lds[t+off];
    __syncthreads();
  }
  if(t==0) bsum[blockIdx.x]=lds[0];
}

__global__ void scan_bsum(int* bsum, int nb){
  __shared__ int lds[1024];
  int t=threadIdx.x;
  int v=(t<nb)?bsum[t]:0;
  lds[t]=v; __syncthreads();
  int x=v;
#pragma unroll
  for(int off=1; off<1024; off<<=1){
    int y=(t>=off)?lds[t-off]:0;
    __syncthreads();
    x+=y; lds[t]=x;
    __syncthreads();
  }
  if(t<nb) bsum[t]=x-v;
}

__global__ void scan_final(const int* __restrict__ counts, const int* __restrict__ bsum,
                           int* __restrict__ row_ptr, int N){
  __shared__ int lds[256];
  int t=threadIdx.x;
  int idx=blockIdx.x*256+t;
  int v=(idx<N)?counts[idx]:0;
  lds[t]=v; __syncthreads();
  int x=v;
#pragma unroll
  for(int off=1; off<256; off<<=1){
    int y=(t>=off)?lds[t-off]:0;
    __syncthreads();
    x+=y; lds[t]=x;
    __syncthreads();
  }
  if(idx<=N) row_ptr[idx]= bsum[blockIdx.x]+x-v;
}

__global__ void fill_k(const int* __restrict__ src, const int* __restrict__ dst,
                       const int* __restrict__ row_ptr, int* __restrict__ cursor,
                       int* __restrict__ csr_src, int E){
  int e = blockIdx.x*blockDim.x + threadIdx.x;
  if(e<E){
    int d = dst[e];
    int pos = row_ptr[d] + atomicAdd(&cursor[d], 1);
    csr_src[pos] = src[e];
  }
}

// ---------------- fused prep: cast X + Wt0/Wt1/biases + dst histogram ----------------
// Wt col order: [Wq(192) | Ws(192) | Wk(192) | Wv(192)]
#define CAST_BLKS (NNODES*DIM_IN/4/256)       // 6250
#define WT0_BLKS  ((QKVRW*DIM_IN+255)/256)    // 384
#define WT1_BLKS  ((QKVRW*HCDIM+255)/256)     // 576
#define HIST_BLKS ((NEDGES+255)/256)          // 3125
__global__ void prep_all(const float* __restrict__ X, unsigned short* __restrict__ Xb,
  const float* __restrict__ Wq0,const float* __restrict__ Wk0,
  const float* __restrict__ Wv0,const float* __restrict__ Ws0,
  const float* __restrict__ bq0,const float* __restrict__ bk0,
  const float* __restrict__ bv0,const float* __restrict__ bs0,
  unsigned short* __restrict__ Wt0, float* __restrict__ bcat0,
  const float* __restrict__ Wq1,const float* __restrict__ Wk1,
  const float* __restrict__ Wv1,const float* __restrict__ Ws1,
  const float* __restrict__ bq1,const float* __restrict__ bk1,
  const float* __restrict__ bv1,const float* __restrict__ bs1,
  unsigned short* __restrict__ Wt1, float* __restrict__ bcat1,
  const int* __restrict__ edst, int* __restrict__ counts)
{
  const int b = blockIdx.x;
  if(b < CAST_BLKS){
    int i4 = (b*256 + threadIdx.x)*4;
    float4 v = *(const float4*)(X+i4);
    ushort4 o; o.x=f2bf(v.x); o.y=f2bf(v.y); o.z=f2bf(v.z); o.w=f2bf(v.w);
    *(ushort4*)(Xb+i4) = o;
  } else if(b < CAST_BLKS+WT0_BLKS){
    int idx = (b-CAST_BLKS)*256 + threadIdx.x;
    if(idx < QKVRW*DIM_IN){
      int c = idx / DIM_IN, k = idx % DIM_IN;
      int mat = c/HCDIM, cm = c%HCDIM;
      const float* W = (mat==0)?Wq0:(mat==1)?Ws0:(mat==2)?Wk0:Wv0;
      Wt0[(size_t)c*DIM_IN + k] = f2bf(W[(size_t)k*HCDIM + cm]);
    }
    if(idx < QKVRW){
      int mat = idx/HCDIM, cm = idx%HCDIM;
      const float* bb = (mat==0)?bq0:(mat==1)?bs0:(mat==2)?bk0:bv0;
      bcat0[idx] = bb[cm];
    }
  } else if(b < CAST_BLKS+WT0_BLKS+WT1_BLKS){
    int idx = (b-CAST_BLKS-WT0_BLKS)*256 + threadIdx.x;
    if(idx < QKVRW*HCDIM){
      int c = idx / HCDIM, k = idx % HCDIM;
      int mat = c/HCDIM, cm = c%HCDIM;
      const float* W = (mat==0)?Wq1:(mat==1)?Ws1:(mat==2)?Wk1:Wv1;
      Wt1[(size_t)c*HCDIM + k] = f2bf(W[(size_t)k*HCDIM + cm]);
    }
    if(idx < QKVRW){
      int mat = idx/HCDIM, cm = idx%HCDIM;
      const float* bb = (mat==0)?bq1:(mat==1)?bs1:(mat==2)?bk1:bv1;
      bcat1[idx] = bb[cm];
    }
  } else {
    int e = (b-CAST_BLKS-WT0_BLKS-WT1_BLKS)*256 + threadIdx.x;
    if(e<NEDGES) atomicAdd(&counts[edst[e]], 1);
  }
}

// ---------------- bf16 MFMA projection GEMM (128x128 tile, BK=64) ----------------
// blockIdx.y 0..5: cols 0-383 (Q|R, bf16 -> QR), 384-767 (K|V, fp8 -> KV interleaved)
// KV row layout (384B): head h at [h*128, h*128+128): dword i: K bytes 8i..8i+3, V bytes 8i+4..8i+7
template<int K>
__global__ __launch_bounds__(256) void gemm_mfma(
    const unsigned short* __restrict__ Xb,
    const unsigned short* __restrict__ Wt,
    const float* __restrict__ bcat,
    unsigned short* __restrict__ QR,
    unsigned char* __restrict__ KV, int N)
{
  __shared__ unsigned short As[128*64];
  __shared__ unsigned short Bs[128*64];
  const int tid = threadIdx.x;
  const int wv = tid>>6;
  const int lane = tid&63;
  const int m0  = blockIdx.x*128;
  const int nc0 = blockIdx.y*128;

  const int wr = wv>>1, wc = wv&1;      // 2x2 waves, wave tile 64(M) x 64(N)
  const int lhi = lane>>4, llo = lane&15;
  f32x4 acc[4][4] = {};

  constexpr int NT = K/64;
#pragma unroll
  for(int kt=0; kt<NT; ++kt){
    if(kt>0) __syncthreads();
#pragma unroll
    for(int it=0; it<4; ++it){
      int p = it*256 + tid;
      int r = p>>3, c = p&7;
      int cs = c ^ (r&7);
      int grow = m0 + r; if(grow > N-1) grow = N-1;
      const unsigned short* gp = Xb + (size_t)grow*K + kt*64 + cs*8;
      unsigned short* lp = As + (size_t)(it*256 + wv*64)*8;
      __builtin_amdgcn_global_load_lds(
          (const __attribute__((address_space(1))) unsigned int*)gp,
          (__attribute__((address_space(3))) unsigned int*)lp, 16, 0, 0);
    }
#pragma unroll
    for(int it=0; it<4; ++it){
      int p = it*256 + tid;
      int r = p>>3, c = p&7;
      int cs = c ^ (r&7);
      const unsigned short* gp = Wt + (size_t)(nc0 + r)*K + kt*64 + cs*8;
      unsigned short* lp = Bs + (size_t)(it*256 + wv*64)*8;
      __builtin_amdgcn_global_load_lds(
          (const __attribute__((address_space(1))) unsigned int*)gp,
          (__attribute__((address_space(3))) unsigned int*)lp, 16, 0, 0);
    }
    __syncthreads();

#pragma unroll
    for(int kk=0; kk<64; kk+=32){
      short8 a[4], b[4];
      const int chunk = (kk>>3) + lhi;
#pragma unroll
      for(int i=0;i<4;++i){
        int rr = wr*64 + i*16 + llo;
        int cs = chunk ^ (rr&7);
        a[i] = *(const short8*)(As + rr*64 + cs*8);
      }
#pragma unroll
      for(int j=0;j<4;++j){
        int cc = wc*64 + j*16 + llo;
        int cs = chunk ^ (cc&7);
        b[j] = *(const short8*)(Bs + cc*64 + cs*8);
      }
#pragma unroll
      for(int i=0;i<4;++i)
#pragma unroll
        for(int j=0;j<4;++j)
          acc[i][j] = __builtin_amdgcn_mfma_f32_16x16x32_bf16(a[i], b[j], acc[i][j], 0,0,0);
    }
  }

  if(nc0 < 384){
#pragma unroll
    for(int j=0;j<4;++j){
      const int col = nc0 + wc*64 + j*16 + llo;
      const float bias = bcat[col];
#pragma unroll
      for(int i=0;i<4;++i){
#pragma unroll
        for(int r=0;r<4;++r){
          int grow = m0 + wr*64 + i*16 + lhi*4 + r;
          if(grow < N) QR[(size_t)grow*384 + col] = f2bf(acc[i][j][r] + bias);
        }
      }
    }
  } else {
#pragma unroll
    for(int j=0;j<4;++j){
      const int c = nc0 - 384 + wc*64 + j*16 + llo;   // 0..383: 0-191 K, 192-383 V
      const float bias = bcat[c + 384];
      // interleaved offset: K: h*128+8i+b ; V: h*128+8i+4+b
      int off;
      if(c < 192){
        off = (c>>6)*128 + ((c&63)>>2)*8 + (c&3);
      } else {
        int c2 = c-192;
        off = (c2>>6)*128 + ((c2&63)>>2)*8 + 4 + (c2&3);
      }
#pragma unroll
      for(int i=0;i<4;++i){
#pragma unroll
        for(int r=0;r<4;++r){
          int grow = m0 + wr*64 + i*16 + lhi*4 + r;
          float v0 = acc[i][j][r] + bias;
          float n0 = __shfl_xor(v0, 1, 64);
          if(((llo&1)==0) && grow < N){
            int p0 = __builtin_amdgcn_cvt_pk_fp8_f32(v0, n0, 0, false);
            *(unsigned short*)(KV + (size_t)grow*384 + off) = (unsigned short)(p0 & 0xffff);
          }
        }
      }
    }
  }
}

// ---------------- single-pass attention + gated skip + ELU ----------------
// Q,R bf16 in QR[N][384]; K,V fp8 interleaved in KV[N][384]
// 1 wave = 1 node; 4 edges in flight, 16 lanes/edge; 1-deep prefetch;
// per head one dwordx2 load: .x = 4 K fp8, .y = 4 V fp8
template<bool OUTBF>
__global__ __launch_bounds__(256) void attn_kernel(
  const unsigned short* __restrict__ QR,
  const unsigned char* __restrict__ KV,
  const int* __restrict__ row_ptr, const int* __restrict__ csr_src,
  const float* __restrict__ Wb, float* __restrict__ HoutF,
  unsigned short* __restrict__ HoutB, int N)
{
  const int wave = threadIdx.x>>6;
  const int lane = threadIdx.x&63;
  const int g    = lane>>4;          // edge slot 0..3
  const int l    = lane&15;          // channel quad 0..15
  const int n = blockIdx.x*4 + wave;
  if(n>=N) return;

  const unsigned short* nr = QR + (size_t)n*384 + 4*l;
  f32x2 qlo[3], qhi[3];
#pragma unroll
  for(int h=0;h<3;++h){
    uint2 u = *(const uint2*)(nr + 64*h);
    qlo[h] = bf2_to_f2(u.x) * 0.125f;
    qhi[h] = bf2_to_f2(u.y) * 0.125f;
  }

  const int s0 = row_ptr[n];
  const int deg = row_ptr[n+1]-s0;

  f32x2 aLo[3] = {{0,0},{0,0},{0,0}};
  f32x2 aHi[3] = {{0,0},{0,0},{0,0}};
  float d0=0.f,d1=0.f,d2=0.f;

  uint2 kv0={0,0}, kv1={0,0}, kv2={0,0};
  if(deg>0){
    int i0 = s0 + (g<deg ? g : 0); if(i0 > NEDGES-1) i0 = NEDGES-1;
    int sCur = csr_src[i0];
    const unsigned char* kb = KV + (size_t)sCur*384 + l*8;
    kv0 = *(const uint2*)(kb);
    kv1 = *(const uint2*)(kb+128);
    kv2 = *(const uint2*)(kb+256);
  }
  for(int base=0; base<deg; base+=4){
    const int inext = base + 4 + g;
    const int sNxt = csr_src[s0 + (inext<deg ? inext : 0)];
    const unsigned char* kbN = KV + (size_t)sNxt*384 + l*8;
    uint2 n0 = *(const uint2*)(kbN);
    uint2 n1 = *(const uint2*)(kbN+128);
    uint2 n2 = *(const uint2*)(kbN+256);

    const bool valid = (base + g < deg);
    f32x2 t0 = qlo[0]*fp8_lo(kv0.x) + qhi[0]*fp8_hi(kv0.x);
    f32x2 t1 = qlo[1]*fp8_lo(kv1.x) + qhi[1]*fp8_hi(kv1.x);
    f32x2 t2 = qlo[2]*fp8_lo(kv2.x) + qhi[2]*fp8_hi(kv2.x);
    float p0 = t0[0]+t0[1];
    float p1 = t1[0]+t1[1];
    float p2 = t2[0]+t2[1];
#pragma unroll
    for(int off=1; off<16; off<<=1){
      p0 += __shfl_xor(p0, off, 64);
      p1 += __shfl_xor(p1, off, 64);
      p2 += __shfl_xor(p2, off, 64);
    }
    float e0 = valid ? __expf(p0) : 0.f;
    float e1 = valid ? __expf(p1) : 0.f;
    float e2 = valid ? __expf(p2) : 0.f;
    d0 += e0; d1 += e1; d2 += e2;
    f32x2 e20 = {e0,e0}, e21 = {e1,e1}, e22 = {e2,e2};
    aLo[0] = fp8_lo(kv0.y)*e20 + aLo[0];
    aHi[0] = fp8_hi(kv0.y)*e20 + aHi[0];
    aLo[1] = fp8_lo(kv1.y)*e21 + aLo[1];
    aHi[1] = fp8_hi(kv1.y)*e21 + aHi[1];
    aLo[2] = fp8_lo(kv2.y)*e22 + aLo[2];
    aHi[2] = fp8_hi(kv2.y)*e22 + aHi[2];

    kv0=n0; kv1=n1; kv2=n2;
  }

  // cross-group reduction (groups hold disjoint edge subsets)
#pragma unroll
  for(int off=16; off<64; off<<=1){
#pragma unroll
    for(int h=0;h<3;++h){
      aLo[h][0]+=__shfl_xor(aLo[h][0],off,64); aLo[h][1]+=__shfl_xor(aLo[h][1],off,64);
      aHi[h][0]+=__shfl_xor(aHi[h][0],off,64); aHi[h][1]+=__shfl_xor(aHi[h][1],off,64);
    }
    d0+=__shfl_xor(d0,off,64); d1+=__shfl_xor(d1,off,64); d2+=__shfl_xor(d2,off,64);
  }
  const float dsum[3] = {d0,d1,d2};
  f32x2 oLo[3], oHi[3], rLo[3], rHi[3];
#pragma unroll
  for(int h=0;h<3;++h){
    float inv = 1.f/(dsum[h]+1e-16f);
    oLo[h] = aLo[h]*inv; oHi[h] = aHi[h]*inv;
    uint2 ur = *(const uint2*)(nr + 192 + 64*h);
    rLo[h] = bf2_to_f2(ur.x); rHi[h] = bf2_to_f2(ur.y);
  }

  f32x2 zz = {0,0};
#pragma unroll
  for(int h=0;h<3;++h){
    const float* wO = Wb + 64*h + 4*l;
    const float* wR = Wb + 192 + 64*h + 4*l;
    const float* wD = Wb + 384 + 64*h + 4*l;
    f32x2 woL = *(const f32x2*)(wO), woH = *(const f32x2*)(wO+2);
    f32x2 wrL = *(const f32x2*)(wR), wrH = *(const f32x2*)(wR+2);
    f32x2 wdL = *(const f32x2*)(wD), wdH = *(const f32x2*)(wD+2);
    zz = oLo[h]*woL + zz;
    zz = oHi[h]*woH + zz;
    zz = rLo[h]*wrL + zz;
    zz = rHi[h]*wrH + zz;
    zz = (oLo[h]-rLo[h])*wdL + zz;
    zz = (oHi[h]-rHi[h])*wdH + zz;
  }
  float z = zz[0]+zz[1];
#pragma unroll
  for(int off=1; off<16; off<<=1) z += __shfl_xor(z, off, 64);
  const float beta = 1.f/(1.f+__expf(-z));

  if(g==0){
#pragma unroll
    for(int h=0;h<3;++h){
      f32x2 hL = (rLo[h]-oLo[h])*beta + oLo[h];
      f32x2 hH = (rHi[h]-oHi[h])*beta + oHi[h];
      hL[0]=(hL[0]>0.f)?hL[0]:expm1f(hL[0]); hL[1]=(hL[1]>0.f)?hL[1]:expm1f(hL[1]);
      hH[0]=(hH[0]>0.f)?hH[0]:expm1f(hH[0]); hH[1]=(hH[1]>0.f)?hH[1]:expm1f(hH[1]);
      if(OUTBF){
        unsigned short* hb = HoutB + (size_t)n*HCDIM + 64*h + 4*l;
        ushort4 u;
        u.x=f2bf(hL[0]); u.y=f2bf(hL[1]); u.z=f2bf(hH[0]); u.w=f2bf(hH[1]);
        *(ushort4*)(hb) = u;
      } else {
        float* ho = HoutF + (size_t)n*HCDIM + 64*h + 4*l;
        float4 f; f.x=hL[0]; f.y=hL[1]; f.z=hH[0]; f.w=hH[1];
        *(float4*)(ho) = f;
      }
    }
  }
}

// ---------------- pooling + logits ----------------
__global__ void pool_k(const float* __restrict__ H, const int* __restrict__ batch,
                       float* __restrict__ pooled, int* __restrict__ cnt, int N){
  const int t = threadIdx.x;       // 192 threads = channel
  int start = blockIdx.x*256;
  int end = min(start+256, N);
  if(start>=N) return;
  int cur = batch[start];
  float acc = 0.f;
  int run = 0;
  for(int nn=start; nn<end; ++nn){
    int g = batch[nn];
    if(g!=cur){
      atomicAdd(&pooled[(size_t)cur*HCDIM+t], acc);
      if(t==0) atomicAdd(&cnt[cur], run);
      acc=0.f; run=0; cur=g;
    }
    acc += H[(size_t)nn*HCDIM+t];
    run++;
  }
  atomicAdd(&pooled[(size_t)cur*HCDIM+t], acc);
  if(t==0) atomicAdd(&cnt[cur], run);
}

__global__ void logits_k(const float* __restrict__ pooled, const int* __restrict__ cnt,
                         const float* __restrict__ Wlin, const float* __restrict__ blin,
                         float* __restrict__ out){
  const int g = blockIdx.x;
  const int lane = threadIdx.x;    // 64 threads
  float c = fmaxf((float)cnt[g], 1.f);
  float s = 0.f;
#pragma unroll
  for(int j=0;j<3;++j){
    int col = j*64+lane;
    s += pooled[(size_t)g*HCDIM+col]/c * Wlin[col];
  }
  s = wave_sum(s);
  if(lane==0) out[g] = s + blin[0];
}

extern "C" void kernel_launch(void* const* d_in, const int* in_sizes, int n_in,
                              void* d_out, int out_size, void* d_ws, size_t ws_size,
                              hipStream_t stream)
{
  const int N=NNODES, E=NEDGES;
  const float* x     = (const float*)d_in[0];
  const int*   ei    = (const int*)d_in[1];
  const int*   batch = (const int*)d_in[2];
  const int* esrc = ei;
  const int* edst = ei + E;
  const float* Wq0=(const float*)d_in[3];  const float* bq0=(const float*)d_in[4];
  const float* Wk0=(const float*)d_in[5];  const float* bk0=(const float*)d_in[6];
  const float* Wv0=(const float*)d_in[7];  const float* bv0=(const float*)d_in[8];
  const float* Ws0=(const float*)d_in[9];  const float* bs0=(const float*)d_in[10];
  const float* Wb0=(const float*)d_in[11];
  const float* Wq1=(const float*)d_in[12]; const float* bq1=(const float*)d_in[13];
  const float* Wk1=(const float*)d_in[14]; const float* bk1=(const float*)d_in[15];
  const float* Wv1=(const float*)d_in[16]; const float* bv1=(const float*)d_in[17];
  const float* Ws1=(const float*)d_in[18]; const float* bs1=(const float*)d_in[19];
  const float* Wb1=(const float*)d_in[20];
  const float* Wlin=(const float*)d_in[21];
  const float* blin=(const float*)d_in[22];
  float* out = (float*)d_out;

  char* p = (char*)d_ws;
  auto alloc = [&](size_t bytes)->char*{
    char* q = p; p += (bytes+255)/256*256; return q;
  };
  unsigned short* Xb   = (unsigned short*)alloc((size_t)N*HCDIM*2);
  unsigned short* QR   = (unsigned short*)alloc((size_t)N*384*2);
  unsigned char*  KV   = (unsigned char*)alloc((size_t)N*384);
  float* H1            = (float*)alloc((size_t)N*HCDIM*4);
  unsigned short* Wt0  = (unsigned short*)alloc((size_t)QKVRW*DIM_IN*2);
  float* bcat0         = (float*)alloc(QKVRW*4);
  unsigned short* Wt1  = (unsigned short*)alloc((size_t)QKVRW*HCDIM*2);
  float* bcat1         = (float*)alloc(QKVRW*4);
  const size_t CSR_CHUNK = ((size_t)N*4+255)/256*256;
  int* counts  = (int*)alloc(CSR_CHUNK);      // counts+cursor contiguous
  int* cursor  = (int*)alloc(CSR_CHUNK);
  int* row_ptr = (int*)alloc((size_t)(N+1)*4);
  int* csr     = (int*)alloc((size_t)E*4);
  int* bsum    = (int*)alloc(4096);
  float* pooled= (float*)alloc((size_t)NGRAPH*HCDIM*4); // pooled+cnt contiguous
  int* cnt     = (int*)alloc(256);

  const int NB = (N+255)/256;

  // ---- async zero-init (graph-capture legal) ----
  hipMemsetAsync(counts, 0, 2*CSR_CHUNK, stream);
  hipMemsetAsync(pooled, 0, (size_t)NGRAPH*HCDIM*4 + 256, stream);

  // ---- fused prep (cast X, Wt0/bcat0, Wt1/bcat1, dst histogram) ----
  prep_all<<<CAST_BLKS + WT0_BLKS + WT1_BLKS + HIST_BLKS, 256, 0, stream>>>(
      x, Xb,
      Wq0,Wk0,Wv0,Ws0, bq0,bk0,bv0,bs0, Wt0, bcat0,
      Wq1,Wk1,Wv1,Ws1, bq1,bk1,bv1,bs1, Wt1, bcat1,
      edst, counts);

  // ---- CSR build ----
  scan_partial<<<NB,256,0,stream>>>(counts,bsum,N);
  scan_bsum<<<1,1024,0,stream>>>(bsum,NB);
  scan_final<<<NB,256,0,stream>>>(counts,bsum,row_ptr,N);
  fill_k<<<(E+255)/256,256,0,stream>>>(esrc,edst,row_ptr,cursor,csr,E);

  dim3 ggemm((N+127)/128, 6);
  // ---- layer 0 ----
  gemm_mfma<DIM_IN><<<ggemm,256,0,stream>>>(Xb,Wt0,bcat0,QR,KV,N);
  attn_kernel<true><<<(N+3)/4,256,0,stream>>>(QR,KV,row_ptr,csr,Wb0,nullptr,Xb,N);
  // ---- layer 1 ----
  gemm_mfma<HCDIM><<<ggemm,256,0,stream>>>(Xb,Wt1,bcat1,QR,KV,N);
  attn_kernel<false><<<(N+3)/4,256,0,stream>>>(QR,KV,row_ptr,csr,Wb1,H1,nullptr,N);

  // ---- pooling + logits ----
  pool_k<<<(N+255)/256,192,0,stream>>>(H1,batch,pooled,cnt,N);
  logits_k<<<NGRAPH,64,0,stream>>>(pooled,cnt,Wlin,blin,out);
}

// Round 11
// 367.463 us; speedup vs baseline: 1.1413x; 1.1413x over previous
//
#include <hip/hip_runtime.h>
#include <math.h>

#define NNODES 50000
#define NEDGES 800000
#define NGRAPH 64
#define DIM_IN 128
#define HCDIM  192
#define QKVRW  768

typedef __attribute__((ext_vector_type(8))) short short8;
typedef __attribute__((ext_vector_type(4))) float f32x4;
typedef __attribute__((ext_vector_type(2))) float f32x2;

__device__ __forceinline__ unsigned short f2bf(float f){
  unsigned int u = __float_as_uint(f);
  unsigned int r = (u + 0x7fffu + ((u>>16)&1u)) >> 16;
  return (unsigned short)r;
}

__device__ __forceinline__ f32x2 bf2_to_f2(unsigned int u){
  f32x2 r;
  r[0] = __uint_as_float(u<<16);
  r[1] = __uint_as_float(u & 0xffff0000u);
  return r;
}

__device__ __forceinline__ f32x2 fp8_lo(unsigned int u){
  return __builtin_amdgcn_cvt_pk_f32_fp8((int)u, false);
}
__device__ __forceinline__ f32x2 fp8_hi(unsigned int u){
  return __builtin_amdgcn_cvt_pk_f32_fp8((int)u, true);
}

__device__ __forceinline__ float wave_sum(float v){
#pragma unroll
  for(int off=32; off>0; off>>=1) v += __shfl_xor(v, off, 64);
  return v;
}

// ---------------- CSR scan kernels ----------------
__global__ void scan_partial(const int* __restrict__ counts, int* __restrict__ bsum, int N){
  __shared__ int lds[256];
  int t = threadIdx.x;
  int idx = blockIdx.x*256 + t;
  int v = (idx<N)? counts[idx] : 0;
  lds[t]=v; __syncthreads();
#pragma unroll
  for(int off=128; off>0; off>>=1){
    if(t<off) lds[t]+=lds[t+off];
    __syncthreads();
  }
  if(t==0) bsum[blockIdx.x]=lds[0];
}

__global__ void scan_bsum(int* bsum, int nb){
  __shared__ int lds[1024];
  int t=threadIdx.x;
  int v=(t<nb)?bsum[t]:0;
  lds[t]=v; __syncthreads();
  int x=v;
#pragma unroll
  for(int off=1; off<1024; off<<=1){
    int y=(t>=off)?lds[t-off]:0;
    __syncthreads();
    x+=y; lds[t]=x;
    __syncthreads();
  }
  if(t<nb) bsum[t]=x-v;
}

__global__ void scan_final(const int* __restrict__ counts, const int* __restrict__ bsum,
                           int* __restrict__ row_ptr, int N){
  __shared__ int lds[256];
  int t=threadIdx.x;
  int idx=blockIdx.x*256+t;
  int v=(idx<N)?counts[idx]:0;
  lds[t]=v; __syncthreads();
  int x=v;
#pragma unroll
  for(int off=1; off<256; off<<=1){
    int y=(t>=off)?lds[t-off]:0;
    __syncthreads();
    x+=y; lds[t]=x;
    __syncthreads();
  }
  if(idx<=N) row_ptr[idx]= bsum[blockIdx.x]+x-v;
}

// counts doubles as cursor: atomicSub returns old (1..deg) -> slot row_ptr[d]+old-1
__global__ void fill_k(const int* __restrict__ src, const int* __restrict__ dst,
                       const int* __restrict__ row_ptr, int* __restrict__ counts,
                       int* __restrict__ csr_src, int E){
  int e = blockIdx.x*blockDim.x + threadIdx.x;
  if(e<E){
    int d = dst[e];
    int pos = row_ptr[d] + atomicSub(&counts[d], 1) - 1;
    csr_src[pos] = src[e];
  }
}

// ---------------- fused prep: cast X + Wt0/Wt1/biases + dst histogram ----------------
// Wt col order: [Wq(192) | Ws(192) | Wk(192) | Wv(192)]
#define CAST_BLKS (NNODES*DIM_IN/4/256)       // 6250
#define WT0_BLKS  ((QKVRW*DIM_IN+255)/256)    // 384
#define WT1_BLKS  ((QKVRW*HCDIM+255)/256)     // 576
#define HIST_BLKS ((NEDGES+255)/256)          // 3125
__global__ void prep_all(const float* __restrict__ X, unsigned short* __restrict__ Xb,
  const float* __restrict__ Wq0,const float* __restrict__ Wk0,
  const float* __restrict__ Wv0,const float* __restrict__ Ws0,
  const float* __restrict__ bq0,const float* __restrict__ bk0,
  const float* __restrict__ bv0,const float* __restrict__ bs0,
  unsigned short* __restrict__ Wt0, float* __restrict__ bcat0,
  const float* __restrict__ Wq1,const float* __restrict__ Wk1,
  const float* __restrict__ Wv1,const float* __restrict__ Ws1,
  const float* __restrict__ bq1,const float* __restrict__ bk1,
  const float* __restrict__ bv1,const float* __restrict__ bs1,
  unsigned short* __restrict__ Wt1, float* __restrict__ bcat1,
  const int* __restrict__ edst, int* __restrict__ counts)
{
  const int b = blockIdx.x;
  if(b < CAST_BLKS){
    int i4 = (b*256 + threadIdx.x)*4;
    float4 v = *(const float4*)(X+i4);
    ushort4 o; o.x=f2bf(v.x); o.y=f2bf(v.y); o.z=f2bf(v.z); o.w=f2bf(v.w);
    *(ushort4*)(Xb+i4) = o;
  } else if(b < CAST_BLKS+WT0_BLKS){
    int idx = (b-CAST_BLKS)*256 + threadIdx.x;
    if(idx < QKVRW*DIM_IN){
      int c = idx / DIM_IN, k = idx % DIM_IN;
      int mat = c/HCDIM, cm = c%HCDIM;
      const float* W = (mat==0)?Wq0:(mat==1)?Ws0:(mat==2)?Wk0:Wv0;
      Wt0[(size_t)c*DIM_IN + k] = f2bf(W[(size_t)k*HCDIM + cm]);
    }
    if(idx < QKVRW){
      int mat = idx/HCDIM, cm = idx%HCDIM;
      const float* bb = (mat==0)?bq0:(mat==1)?bs0:(mat==2)?bk0:bv0;
      bcat0[idx] = bb[cm];
    }
  } else if(b < CAST_BLKS+WT0_BLKS+WT1_BLKS){
    int idx = (b-CAST_BLKS-WT0_BLKS)*256 + threadIdx.x;
    if(idx < QKVRW*HCDIM){
      int c = idx / HCDIM, k = idx % HCDIM;
      int mat = c/HCDIM, cm = c%HCDIM;
      const float* W = (mat==0)?Wq1:(mat==1)?Ws1:(mat==2)?Wk1:Wv1;
      Wt1[(size_t)c*HCDIM + k] = f2bf(W[(size_t)k*HCDIM + cm]);
    }
    if(idx < QKVRW){
      int mat = idx/HCDIM, cm = idx%HCDIM;
      const float* bb = (mat==0)?bq1:(mat==1)?bs1:(mat==2)?bk1:bv1;
      bcat1[idx] = bb[cm];
    }
  } else {
    int e = (b-CAST_BLKS-WT0_BLKS-WT1_BLKS)*256 + threadIdx.x;
    if(e<NEDGES) atomicAdd(&counts[edst[e]], 1);
  }
}

// ---------------- bf16 MFMA projection GEMM (128x128 tile, BK=64) ----------------
// blockIdx.y 0..5: cols 0-383 (Q|R, bf16 -> QR), 384-767 (K|V, fp8 -> KV interleaved)
// KV row layout (384B): head h at [h*128, h*128+128): dword i: K bytes 8i..8i+3, V bytes 8i+4..8i+7
template<int K>
__global__ __launch_bounds__(256) void gemm_mfma(
    const unsigned short* __restrict__ Xb,
    const unsigned short* __restrict__ Wt,
    const float* __restrict__ bcat,
    unsigned short* __restrict__ QR,
    unsigned char* __restrict__ KV, int N)
{
  __shared__ unsigned short As[128*64];
  __shared__ unsigned short Bs[128*64];
  const int tid = threadIdx.x;
  const int wv = tid>>6;
  const int lane = tid&63;
  const int m0  = blockIdx.x*128;
  const int nc0 = blockIdx.y*128;

  const int wr = wv>>1, wc = wv&1;      // 2x2 waves, wave tile 64(M) x 64(N)
  const int lhi = lane>>4, llo = lane&15;
  f32x4 acc[4][4] = {};

  constexpr int NT = K/64;
#pragma unroll
  for(int kt=0; kt<NT; ++kt){
    if(kt>0) __syncthreads();
#pragma unroll
    for(int it=0; it<4; ++it){
      int p = it*256 + tid;
      int r = p>>3, c = p&7;
      int cs = c ^ (r&7);
      int grow = m0 + r; if(grow > N-1) grow = N-1;
      const unsigned short* gp = Xb + (size_t)grow*K + kt*64 + cs*8;
      unsigned short* lp = As + (size_t)(it*256 + wv*64)*8;
      __builtin_amdgcn_global_load_lds(
          (const __attribute__((address_space(1))) unsigned int*)gp,
          (__attribute__((address_space(3))) unsigned int*)lp, 16, 0, 0);
    }
#pragma unroll
    for(int it=0; it<4; ++it){
      int p = it*256 + tid;
      int r = p>>3, c = p&7;
      int cs = c ^ (r&7);
      const unsigned short* gp = Wt + (size_t)(nc0 + r)*K + kt*64 + cs*8;
      unsigned short* lp = Bs + (size_t)(it*256 + wv*64)*8;
      __builtin_amdgcn_global_load_lds(
          (const __attribute__((address_space(1))) unsigned int*)gp,
          (__attribute__((address_space(3))) unsigned int*)lp, 16, 0, 0);
    }
    __syncthreads();

#pragma unroll
    for(int kk=0; kk<64; kk+=32){
      short8 a[4], b[4];
      const int chunk = (kk>>3) + lhi;
#pragma unroll
      for(int i=0;i<4;++i){
        int rr = wr*64 + i*16 + llo;
        int cs = chunk ^ (rr&7);
        a[i] = *(const short8*)(As + rr*64 + cs*8);
      }
#pragma unroll
      for(int j=0;j<4;++j){
        int cc = wc*64 + j*16 + llo;
        int cs = chunk ^ (cc&7);
        b[j] = *(const short8*)(Bs + cc*64 + cs*8);
      }
#pragma unroll
      for(int i=0;i<4;++i)
#pragma unroll
        for(int j=0;j<4;++j)
          acc[i][j] = __builtin_amdgcn_mfma_f32_16x16x32_bf16(a[i], b[j], acc[i][j], 0,0,0);
    }
  }

  if(nc0 < 384){
#pragma unroll
    for(int j=0;j<4;++j){
      const int col = nc0 + wc*64 + j*16 + llo;
      const float bias = bcat[col];
#pragma unroll
      for(int i=0;i<4;++i){
#pragma unroll
        for(int r=0;r<4;++r){
          int grow = m0 + wr*64 + i*16 + lhi*4 + r;
          if(grow < N) QR[(size_t)grow*384 + col] = f2bf(acc[i][j][r] + bias);
        }
      }
    }
  } else {
#pragma unroll
    for(int j=0;j<4;++j){
      const int c = nc0 - 384 + wc*64 + j*16 + llo;   // 0..383: 0-191 K, 192-383 V
      const float bias = bcat[c + 384];
      int off;
      if(c < 192){
        off = (c>>6)*128 + ((c&63)>>2)*8 + (c&3);
      } else {
        int c2 = c-192;
        off = (c2>>6)*128 + ((c2&63)>>2)*8 + 4 + (c2&3);
      }
#pragma unroll
      for(int i=0;i<4;++i){
#pragma unroll
        for(int r=0;r<4;++r){
          int grow = m0 + wr*64 + i*16 + lhi*4 + r;
          float v0 = acc[i][j][r] + bias;
          float n0 = __shfl_xor(v0, 1, 64);
          if(((llo&1)==0) && grow < N){
            int p0 = __builtin_amdgcn_cvt_pk_fp8_f32(v0, n0, 0, false);
            *(unsigned short*)(KV + (size_t)grow*384 + off) = (unsigned short)(p0 & 0xffff);
          }
        }
      }
    }
  }
}

// ---------------- single-pass attention + gated skip + ELU ----------------
// Q,R bf16 in QR[N][384]; K,V fp8 interleaved in KV[N][384]
// 1 wave = 1 node; 4 edges in flight, 16 lanes/edge; 2-deep KV prefetch pipeline
template<bool OUTBF>
__global__ __launch_bounds__(256) void attn_kernel(
  const unsigned short* __restrict__ QR,
  const unsigned char* __restrict__ KV,
  const int* __restrict__ row_ptr, const int* __restrict__ csr_src,
  const float* __restrict__ Wb, float* __restrict__ HoutF,
  unsigned short* __restrict__ HoutB, int N)
{
  const int wave = threadIdx.x>>6;
  const int lane = threadIdx.x&63;
  const int g    = lane>>4;          // edge slot 0..3
  const int l    = lane&15;          // channel quad 0..15
  const int n = blockIdx.x*4 + wave;
  if(n>=N) return;

  const unsigned short* nr = QR + (size_t)n*384 + 4*l;
  f32x2 qlo[3], qhi[3];
#pragma unroll
  for(int h=0;h<3;++h){
    uint2 u = *(const uint2*)(nr + 64*h);
    qlo[h] = bf2_to_f2(u.x) * 0.125f;
    qhi[h] = bf2_to_f2(u.y) * 0.125f;
  }

  const int s0 = row_ptr[n];
  const int deg = row_ptr[n+1]-s0;

  f32x2 aLo[3] = {{0,0},{0,0},{0,0}};
  f32x2 aHi[3] = {{0,0},{0,0},{0,0}};
  float d0=0.f,d1=0.f,d2=0.f;

  // 2-deep prefetch pipeline: A = iter i data, B = iter i+1 data
  uint2 A0={0,0},A1={0,0},A2={0,0};
  uint2 B0={0,0},B1={0,0},B2={0,0};
  if(deg>0){
    int sA = csr_src[s0 + (g<deg ? g : 0)];
    const unsigned char* ka = KV + (size_t)sA*384 + l*8;
    A0 = *(const uint2*)(ka);
    A1 = *(const uint2*)(ka+128);
    A2 = *(const uint2*)(ka+256);
    int ib = 4+g;
    int sB = csr_src[s0 + (ib<deg ? ib : 0)];
    const unsigned char* kb = KV + (size_t)sB*384 + l*8;
    B0 = *(const uint2*)(kb);
    B1 = *(const uint2*)(kb+128);
    B2 = *(const uint2*)(kb+256);
  }
  for(int base=0; base<deg; base+=4){
    // issue loads for iter i+2
    const int ic = base + 8 + g;
    const int sC = csr_src[s0 + (ic<deg ? ic : 0)];
    const unsigned char* kc = KV + (size_t)sC*384 + l*8;
    uint2 C0 = *(const uint2*)(kc);
    uint2 C1 = *(const uint2*)(kc+128);
    uint2 C2 = *(const uint2*)(kc+256);

    const bool valid = (base + g < deg);
    f32x2 t0 = qlo[0]*fp8_lo(A0.x) + qhi[0]*fp8_hi(A0.x);
    f32x2 t1 = qlo[1]*fp8_lo(A1.x) + qhi[1]*fp8_hi(A1.x);
    f32x2 t2 = qlo[2]*fp8_lo(A2.x) + qhi[2]*fp8_hi(A2.x);
    float p0 = t0[0]+t0[1];
    float p1 = t1[0]+t1[1];
    float p2 = t2[0]+t2[1];
#pragma unroll
    for(int off=1; off<16; off<<=1){
      p0 += __shfl_xor(p0, off, 64);
      p1 += __shfl_xor(p1, off, 64);
      p2 += __shfl_xor(p2, off, 64);
    }
    float e0 = valid ? __expf(p0) : 0.f;
    float e1 = valid ? __expf(p1) : 0.f;
    float e2 = valid ? __expf(p2) : 0.f;
    d0 += e0; d1 += e1; d2 += e2;
    f32x2 e20 = {e0,e0}, e21 = {e1,e1}, e22 = {e2,e2};
    aLo[0] = fp8_lo(A0.y)*e20 + aLo[0];
    aHi[0] = fp8_hi(A0.y)*e20 + aHi[0];
    aLo[1] = fp8_lo(A1.y)*e21 + aLo[1];
    aHi[1] = fp8_hi(A1.y)*e21 + aHi[1];
    aLo[2] = fp8_lo(A2.y)*e22 + aLo[2];
    aHi[2] = fp8_hi(A2.y)*e22 + aHi[2];

    A0=B0; A1=B1; A2=B2;
    B0=C0; B1=C1; B2=C2;
  }

  // cross-group reduction (groups hold disjoint edge subsets)
#pragma unroll
  for(int off=16; off<64; off<<=1){
#pragma unroll
    for(int h=0;h<3;++h){
      aLo[h][0]+=__shfl_xor(aLo[h][0],off,64); aLo[h][1]+=__shfl_xor(aLo[h][1],off,64);
      aHi[h][0]+=__shfl_xor(aHi[h][0],off,64); aHi[h][1]+=__shfl_xor(aHi[h][1],off,64);
    }
    d0+=__shfl_xor(d0,off,64); d1+=__shfl_xor(d1,off,64); d2+=__shfl_xor(d2,off,64);
  }
  const float dsum[3] = {d0,d1,d2};
  f32x2 oLo[3], oHi[3], rLo[3], rHi[3];
#pragma unroll
  for(int h=0;h<3;++h){
    float inv = 1.f/(dsum[h]+1e-16f);
    oLo[h] = aLo[h]*inv; oHi[h] = aHi[h]*inv;
    uint2 ur = *(const uint2*)(nr + 192 + 64*h);
    rLo[h] = bf2_to_f2(ur.x); rHi[h] = bf2_to_f2(ur.y);
  }

  f32x2 zz = {0,0};
#pragma unroll
  for(int h=0;h<3;++h){
    const float* wO = Wb + 64*h + 4*l;
    const float* wR = Wb + 192 + 64*h + 4*l;
    const float* wD = Wb + 384 + 64*h + 4*l;
    f32x2 woL = *(const f32x2*)(wO), woH = *(const f32x2*)(wO+2);
    f32x2 wrL = *(const f32x2*)(wR), wrH = *(const f32x2*)(wR+2);
    f32x2 wdL = *(const f32x2*)(wD), wdH = *(const f32x2*)(wD+2);
    zz = oLo[h]*woL + zz;
    zz = oHi[h]*woH + zz;
    zz = rLo[h]*wrL + zz;
    zz = rHi[h]*wrH + zz;
    zz = (oLo[h]-rLo[h])*wdL + zz;
    zz = (oHi[h]-rHi[h])*wdH + zz;
  }
  float z = zz[0]+zz[1];
#pragma unroll
  for(int off=1; off<16; off<<=1) z += __shfl_xor(z, off, 64);
  const float beta = 1.f/(1.f+__expf(-z));

  if(g==0){
#pragma unroll
    for(int h=0;h<3;++h){
      f32x2 hL = (rLo[h]-oLo[h])*beta + oLo[h];
      f32x2 hH = (rHi[h]-oHi[h])*beta + oHi[h];
      hL[0]=(hL[0]>0.f)?hL[0]:expm1f(hL[0]); hL[1]=(hL[1]>0.f)?hL[1]:expm1f(hL[1]);
      hH[0]=(hH[0]>0.f)?hH[0]:expm1f(hH[0]); hH[1]=(hH[1]>0.f)?hH[1]:expm1f(hH[1]);
      if(OUTBF){
        unsigned short* hb = HoutB + (size_t)n*HCDIM + 64*h + 4*l;
        ushort4 u;
        u.x=f2bf(hL[0]); u.y=f2bf(hL[1]); u.z=f2bf(hH[0]); u.w=f2bf(hH[1]);
        *(ushort4*)(hb) = u;
      } else {
        float* ho = HoutF + (size_t)n*HCDIM + 64*h + 4*l;
        float4 f; f.x=hL[0]; f.y=hL[1]; f.z=hH[0]; f.w=hH[1];
        *(float4*)(ho) = f;
      }
    }
  }
}

// ---------------- pooling + logits ----------------
// 64 nodes per block (4x parallelism vs 256/block); batch sorted -> ~1-2 runs/block
__global__ void pool_k(const float* __restrict__ H, const int* __restrict__ batch,
                       float* __restrict__ pooled, int* __restrict__ cnt, int N){
  const int t = threadIdx.x;       // 192 threads = channel
  int start = blockIdx.x*64;
  int end = min(start+64, N);
  if(start>=N) return;
  int cur = batch[start];
  float acc = 0.f;
  int run = 0;
  for(int nn=start; nn<end; ++nn){
    int g = batch[nn];
    if(g!=cur){
      atomicAdd(&pooled[(size_t)cur*HCDIM+t], acc);
      if(t==0) atomicAdd(&cnt[cur], run);
      acc=0.f; run=0; cur=g;
    }
    acc += H[(size_t)nn*HCDIM+t];
    run++;
  }
  atomicAdd(&pooled[(size_t)cur*HCDIM+t], acc);
  if(t==0) atomicAdd(&cnt[cur], run);
}

__global__ void logits_k(const float* __restrict__ pooled, const int* __restrict__ cnt,
                         const float* __restrict__ Wlin, const float* __restrict__ blin,
                         float* __restrict__ out){
  const int g = blockIdx.x;
  const int lane = threadIdx.x;    // 64 threads
  float c = fmaxf((float)cnt[g], 1.f);
  float s = 0.f;
#pragma unroll
  for(int j=0;j<3;++j){
    int col = j*64+lane;
    s += pooled[(size_t)g*HCDIM+col]/c * Wlin[col];
  }
  s = wave_sum(s);
  if(lane==0) out[g] = s + blin[0];
}

extern "C" void kernel_launch(void* const* d_in, const int* in_sizes, int n_in,
                              void* d_out, int out_size, void* d_ws, size_t ws_size,
                              hipStream_t stream)
{
  const int N=NNODES, E=NEDGES;
  const float* x     = (const float*)d_in[0];
  const int*   ei    = (const int*)d_in[1];
  const int*   batch = (const int*)d_in[2];
  const int* esrc = ei;
  const int* edst = ei + E;
  const float* Wq0=(const float*)d_in[3];  const float* bq0=(const float*)d_in[4];
  const float* Wk0=(const float*)d_in[5];  const float* bk0=(const float*)d_in[6];
  const float* Wv0=(const float*)d_in[7];  const float* bv0=(const float*)d_in[8];
  const float* Ws0=(const float*)d_in[9];  const float* bs0=(const float*)d_in[10];
  const float* Wb0=(const float*)d_in[11];
  const float* Wq1=(const float*)d_in[12]; const float* bq1=(const float*)d_in[13];
  const float* Wk1=(const float*)d_in[14]; const float* bk1=(const float*)d_in[15];
  const float* Wv1=(const float*)d_in[16]; const float* bv1=(const float*)d_in[17];
  const float* Ws1=(const float*)d_in[18]; const float* bs1=(const float*)d_in[19];
  const float* Wb1=(const float*)d_in[20];
  const float* Wlin=(const float*)d_in[21];
  const float* blin=(const float*)d_in[22];
  float* out = (float*)d_out;

  char* p = (char*)d_ws;
  auto alloc = [&](size_t bytes)->char*{
    char* q = p; p += (bytes+255)/256*256; return q;
  };
  unsigned short* Xb   = (unsigned short*)alloc((size_t)N*HCDIM*2);
  unsigned short* QR   = (unsigned short*)alloc((size_t)N*384*2);
  unsigned char*  KV   = (unsigned char*)alloc((size_t)N*384);
  float* H1            = (float*)alloc((size_t)N*HCDIM*4);
  unsigned short* Wt0  = (unsigned short*)alloc((size_t)QKVRW*DIM_IN*2);
  float* bcat0         = (float*)alloc(QKVRW*4);
  unsigned short* Wt1  = (unsigned short*)alloc((size_t)QKVRW*HCDIM*2);
  float* bcat1         = (float*)alloc(QKVRW*4);
  const size_t CSR_CHUNK = ((size_t)N*4+255)/256*256;
  int* counts  = (int*)alloc(CSR_CHUNK);
  int* row_ptr = (int*)alloc((size_t)(N+1)*4);
  int* csr     = (int*)alloc((size_t)E*4);
  int* bsum    = (int*)alloc(4096);
  float* pooled= (float*)alloc((size_t)NGRAPH*HCDIM*4); // pooled+cnt contiguous
  int* cnt     = (int*)alloc(256);

  const int NB = (N+255)/256;

  // ---- async zero-init (graph-capture legal) ----
  hipMemsetAsync(counts, 0, CSR_CHUNK, stream);
  hipMemsetAsync(pooled, 0, (size_t)NGRAPH*HCDIM*4 + 256, stream);

  // ---- fused prep (cast X, Wt0/bcat0, Wt1/bcat1, dst histogram) ----
  prep_all<<<CAST_BLKS + WT0_BLKS + WT1_BLKS + HIST_BLKS, 256, 0, stream>>>(
      x, Xb,
      Wq0,Wk0,Wv0,Ws0, bq0,bk0,bv0,bs0, Wt0, bcat0,
      Wq1,Wk1,Wv1,Ws1, bq1,bk1,bv1,bs1, Wt1, bcat1,
      edst, counts);

  // ---- CSR build ----
  scan_partial<<<NB,256,0,stream>>>(counts,bsum,N);
  scan_bsum<<<1,1024,0,stream>>>(bsum,NB);
  scan_final<<<NB,256,0,stream>>>(counts,bsum,row_ptr,N);
  fill_k<<<(E+255)/256,256,0,stream>>>(esrc,edst,row_ptr,counts,csr,E);

  dim3 ggemm((N+127)/128, 6);
  // ---- layer 0 ----
  gemm_mfma<DIM_IN><<<ggemm,256,0,stream>>>(Xb,Wt0,bcat0,QR,KV,N);
  attn_kernel<true><<<(N+3)/4,256,0,stream>>>(QR,KV,row_ptr,csr,Wb0,nullptr,Xb,N);
  // ---- layer 1 ----
  gemm_mfma<HCDIM><<<ggemm,256,0,stream>>>(Xb,Wt1,bcat1,QR,KV,N);
  attn_kernel<false><<<(N+3)/4,256,0,stream>>>(QR,KV,row_ptr,csr,Wb1,H1,nullptr,N);

  // ---- pooling + logits ----
  pool_k<<<(N+63)/64,192,0,stream>>>(H1,batch,pooled,cnt,N);
  logits_k<<<NGRAPH,64,0,stream>>>(pooled,cnt,Wlin,blin,out);
}

// Round 12
// 356.259 us; speedup vs baseline: 1.1772x; 1.0314x over previous
//
#include <hip/hip_runtime.h>
#include <math.h>

#define NNODES 50000
#define NEDGES 800000
#define NGRAPH 64
#define DIM_IN 128
#define HCDIM  192
#define QKVRW  768

typedef __attribute__((ext_vector_type(8))) short short8;
typedef __attribute__((ext_vector_type(4))) float f32x4;
typedef __attribute__((ext_vector_type(2))) float f32x2;

__device__ __forceinline__ unsigned short f2bf(float f){
  unsigned int u = __float_as_uint(f);
  unsigned int r = (u + 0x7fffu + ((u>>16)&1u)) >> 16;
  return (unsigned short)r;
}

__device__ __forceinline__ f32x2 bf2_to_f2(unsigned int u){
  f32x2 r;
  r[0] = __uint_as_float(u<<16);
  r[1] = __uint_as_float(u & 0xffff0000u);
  return r;
}

__device__ __forceinline__ f32x2 fp8_lo(unsigned int u){
  return __builtin_amdgcn_cvt_pk_f32_fp8((int)u, false);
}
__device__ __forceinline__ f32x2 fp8_hi(unsigned int u){
  return __builtin_amdgcn_cvt_pk_f32_fp8((int)u, true);
}

__device__ __forceinline__ float wave_sum(float v){
#pragma unroll
  for(int off=32; off>0; off>>=1) v += __shfl_xor(v, off, 64);
  return v;
}

// ---------------- CSR scan kernels ----------------
__global__ void scan_partial(const int* __restrict__ counts, int* __restrict__ bsum, int N){
  __shared__ int lds[256];
  int t = threadIdx.x;
  int idx = blockIdx.x*256 + t;
  int v = (idx<N)? counts[idx] : 0;
  lds[t]=v; __syncthreads();
#pragma unroll
  for(int off=128; off>0; off>>=1){
    if(t<off) lds[t]+=lds[t+off];
    __syncthreads();
  }
  if(t==0) bsum[blockIdx.x]=lds[0];
}

// fused: per-block prefix of bsum (raw block sums) + local scan
__global__ void scan_final(const int* __restrict__ counts, const int* __restrict__ bsum,
                           int* __restrict__ row_ptr, int N){
  __shared__ int lds[256];
  __shared__ int red[4];
  const int t=threadIdx.x;
  const int idx=blockIdx.x*256+t;
  int part=0;
  for(int i=t;i<blockIdx.x;i+=256) part += bsum[i];
#pragma unroll
  for(int off=32; off>0; off>>=1) part += __shfl_xor(part, off, 64);
  if((t&63)==0) red[t>>6]=part;
  __syncthreads();
  const int base = red[0]+red[1]+red[2]+red[3];
  int v=(idx<N)?counts[idx]:0;
  lds[t]=v; __syncthreads();
  int x=v;
#pragma unroll
  for(int off=1; off<256; off<<=1){
    int y=(t>=off)?lds[t-off]:0;
    __syncthreads();
    x+=y; lds[t]=x;
    __syncthreads();
  }
  if(idx<=N) row_ptr[idx]= base+x-v;
}

// counts doubles as cursor: atomicSub returns old (1..deg) -> slot row_ptr[d]+old-1
__global__ void fill_k(const int* __restrict__ src, const int* __restrict__ dst,
                       const int* __restrict__ row_ptr, int* __restrict__ counts,
                       int* __restrict__ csr_src, int E){
  int e = blockIdx.x*blockDim.x + threadIdx.x;
  if(e<E){
    int d = dst[e];
    int pos = row_ptr[d] + atomicSub(&counts[d], 1) - 1;
    csr_src[pos] = src[e];
  }
}

// ---------------- fused prep: cast X + Wt0/Wt1/biases + dst histogram ----------------
// Wt col order: [Wq(192) | Ws(192) | Wk(192) | Wv(192)]
#define CAST_BLKS (NNODES*DIM_IN/4/256)       // 6250
#define WT0_BLKS  ((QKVRW*DIM_IN+255)/256)    // 384
#define WT1_BLKS  ((QKVRW*HCDIM+255)/256)     // 576
#define HIST_BLKS ((NEDGES+255)/256)          // 3125
__global__ void prep_all(const float* __restrict__ X, unsigned short* __restrict__ Xb,
  const float* __restrict__ Wq0,const float* __restrict__ Wk0,
  const float* __restrict__ Wv0,const float* __restrict__ Ws0,
  const float* __restrict__ bq0,const float* __restrict__ bk0,
  const float* __restrict__ bv0,const float* __restrict__ bs0,
  unsigned short* __restrict__ Wt0, float* __restrict__ bcat0,
  const float* __restrict__ Wq1,const float* __restrict__ Wk1,
  const float* __restrict__ Wv1,const float* __restrict__ Ws1,
  const float* __restrict__ bq1,const float* __restrict__ bk1,
  const float* __restrict__ bv1,const float* __restrict__ bs1,
  unsigned short* __restrict__ Wt1, float* __restrict__ bcat1,
  const int* __restrict__ edst, int* __restrict__ counts)
{
  const int b = blockIdx.x;
  if(b < CAST_BLKS){
    int i4 = (b*256 + threadIdx.x)*4;
    float4 v = *(const float4*)(X+i4);
    ushort4 o; o.x=f2bf(v.x); o.y=f2bf(v.y); o.z=f2bf(v.z); o.w=f2bf(v.w);
    *(ushort4*)(Xb+i4) = o;
  } else if(b < CAST_BLKS+WT0_BLKS){
    int idx = (b-CAST_BLKS)*256 + threadIdx.x;
    if(idx < QKVRW*DIM_IN){
      int c = idx / DIM_IN, k = idx % DIM_IN;
      int mat = c/HCDIM, cm = c%HCDIM;
      const float* W = (mat==0)?Wq0:(mat==1)?Ws0:(mat==2)?Wk0:Wv0;
      Wt0[(size_t)c*DIM_IN + k] = f2bf(W[(size_t)k*HCDIM + cm]);
    }
    if(idx < QKVRW){
      int mat = idx/HCDIM, cm = idx%HCDIM;
      const float* bb = (mat==0)?bq0:(mat==1)?bs0:(mat==2)?bk0:bv0;
      bcat0[idx] = bb[cm];
    }
  } else if(b < CAST_BLKS+WT0_BLKS+WT1_BLKS){
    int idx = (b-CAST_BLKS-WT0_BLKS)*256 + threadIdx.x;
    if(idx < QKVRW*HCDIM){
      int c = idx / HCDIM, k = idx % HCDIM;
      int mat = c/HCDIM, cm = c%HCDIM;
      const float* W = (mat==0)?Wq1:(mat==1)?Ws1:(mat==2)?Wk1:Wv1;
      Wt1[(size_t)c*HCDIM + k] = f2bf(W[(size_t)k*HCDIM + cm]);
    }
    if(idx < QKVRW){
      int mat = idx/HCDIM, cm = idx%HCDIM;
      const float* bb = (mat==0)?bq1:(mat==1)?bs1:(mat==2)?bk1:bv1;
      bcat1[idx] = bb[cm];
    }
  } else {
    int e = (b-CAST_BLKS-WT0_BLKS-WT1_BLKS)*256 + threadIdx.x;
    if(e<NEDGES) atomicAdd(&counts[edst[e]], 1);
  }
}

// ---------------- bf16 MFMA projection GEMM (128x128 tile, BK=64) ----------------
// blockIdx.y 0..5: cols 0-383 (Q|R, bf16 -> QR), 384-767 (K|V, fp8 -> KV interleaved)
// KV row layout (384B): head h at [h*128, h*128+128): dword i: K bytes 8i..8i+3, V bytes 8i+4..8i+7
template<int K>
__global__ __launch_bounds__(256) void gemm_mfma(
    const unsigned short* __restrict__ Xb,
    const unsigned short* __restrict__ Wt,
    const float* __restrict__ bcat,
    unsigned short* __restrict__ QR,
    unsigned char* __restrict__ KV, int N)
{
  __shared__ unsigned short As[128*64];
  __shared__ unsigned short Bs[128*64];
  const int tid = threadIdx.x;
  const int wv = tid>>6;
  const int lane = tid&63;
  const int m0  = blockIdx.x*128;
  const int nc0 = blockIdx.y*128;

  const int wr = wv>>1, wc = wv&1;      // 2x2 waves, wave tile 64(M) x 64(N)
  const int lhi = lane>>4, llo = lane&15;
  f32x4 acc[4][4] = {};

  constexpr int NT = K/64;
#pragma unroll
  for(int kt=0; kt<NT; ++kt){
    if(kt>0) __syncthreads();
#pragma unroll
    for(int it=0; it<4; ++it){
      int p = it*256 + tid;
      int r = p>>3, c = p&7;
      int cs = c ^ (r&7);
      int grow = m0 + r; if(grow > N-1) grow = N-1;
      const unsigned short* gp = Xb + (size_t)grow*K + kt*64 + cs*8;
      unsigned short* lp = As + (size_t)(it*256 + wv*64)*8;
      __builtin_amdgcn_global_load_lds(
          (const __attribute__((address_space(1))) unsigned int*)gp,
          (__attribute__((address_space(3))) unsigned int*)lp, 16, 0, 0);
    }
#pragma unroll
    for(int it=0; it<4; ++it){
      int p = it*256 + tid;
      int r = p>>3, c = p&7;
      int cs = c ^ (r&7);
      const unsigned short* gp = Wt + (size_t)(nc0 + r)*K + kt*64 + cs*8;
      unsigned short* lp = Bs + (size_t)(it*256 + wv*64)*8;
      __builtin_amdgcn_global_load_lds(
          (const __attribute__((address_space(1))) unsigned int*)gp,
          (__attribute__((address_space(3))) unsigned int*)lp, 16, 0, 0);
    }
    __syncthreads();

#pragma unroll
    for(int kk=0; kk<64; kk+=32){
      short8 a[4], b[4];
      const int chunk = (kk>>3) + lhi;
#pragma unroll
      for(int i=0;i<4;++i){
        int rr = wr*64 + i*16 + llo;
        int cs = chunk ^ (rr&7);
        a[i] = *(const short8*)(As + rr*64 + cs*8);
      }
#pragma unroll
      for(int j=0;j<4;++j){
        int cc = wc*64 + j*16 + llo;
        int cs = chunk ^ (cc&7);
        b[j] = *(const short8*)(Bs + cc*64 + cs*8);
      }
#pragma unroll
      for(int i=0;i<4;++i)
#pragma unroll
        for(int j=0;j<4;++j)
          acc[i][j] = __builtin_amdgcn_mfma_f32_16x16x32_bf16(a[i], b[j], acc[i][j], 0,0,0);
    }
  }

  if(nc0 < 384){
#pragma unroll
    for(int j=0;j<4;++j){
      const int col = nc0 + wc*64 + j*16 + llo;
      const float bias = bcat[col];
#pragma unroll
      for(int i=0;i<4;++i){
#pragma unroll
        for(int r=0;r<4;++r){
          int grow = m0 + wr*64 + i*16 + lhi*4 + r;
          if(grow < N) QR[(size_t)grow*384 + col] = f2bf(acc[i][j][r] + bias);
        }
      }
    }
  } else {
#pragma unroll
    for(int j=0;j<4;++j){
      const int c = nc0 - 384 + wc*64 + j*16 + llo;   // 0..383: 0-191 K, 192-383 V
      const float bias = bcat[c + 384];
      int off;
      if(c < 192){
        off = (c>>6)*128 + ((c&63)>>2)*8 + (c&3);
      } else {
        int c2 = c-192;
        off = (c2>>6)*128 + ((c2&63)>>2)*8 + 4 + (c2&3);
      }
#pragma unroll
      for(int i=0;i<4;++i){
#pragma unroll
        for(int r=0;r<4;++r){
          int grow = m0 + wr*64 + i*16 + lhi*4 + r;
          float v0 = acc[i][j][r] + bias;
          float n0 = __shfl_xor(v0, 1, 64);
          if(((llo&1)==0) && grow < N){
            int p0 = __builtin_amdgcn_cvt_pk_fp8_f32(v0, n0, 0, false);
            *(unsigned short*)(KV + (size_t)grow*384 + off) = (unsigned short)(p0 & 0xffff);
          }
        }
      }
    }
  }
}

// ---------------- single-pass attention + gated skip + ELU ----------------
// Q,R bf16 in QR[N][384]; K,V fp8 interleaved in KV[N][384]
// 1 wave = 1 node; 4 edges in flight, 16 lanes/edge; 1-deep prefetch (proven best)
template<bool OUTBF>
__global__ __launch_bounds__(256) void attn_kernel(
  const unsigned short* __restrict__ QR,
  const unsigned char* __restrict__ KV,
  const int* __restrict__ row_ptr, const int* __restrict__ csr_src,
  const float* __restrict__ Wb, float* __restrict__ HoutF,
  unsigned short* __restrict__ HoutB, int N)
{
  const int wave = threadIdx.x>>6;
  const int lane = threadIdx.x&63;
  const int g    = lane>>4;          // edge slot 0..3
  const int l    = lane&15;          // channel quad 0..15
  const int n = blockIdx.x*4 + wave;
  if(n>=N) return;

  const unsigned short* nr = QR + (size_t)n*384 + 4*l;
  f32x2 qlo[3], qhi[3];
#pragma unroll
  for(int h=0;h<3;++h){
    uint2 u = *(const uint2*)(nr + 64*h);
    qlo[h] = bf2_to_f2(u.x) * 0.125f;
    qhi[h] = bf2_to_f2(u.y) * 0.125f;
  }

  const int s0 = row_ptr[n];
  const int deg = row_ptr[n+1]-s0;

  f32x2 aLo[3] = {{0,0},{0,0},{0,0}};
  f32x2 aHi[3] = {{0,0},{0,0},{0,0}};
  float d0=0.f,d1=0.f,d2=0.f;

  uint2 kv0={0,0}, kv1={0,0}, kv2={0,0};
  if(deg>0){
    int i0 = s0 + (g<deg ? g : 0); if(i0 > NEDGES-1) i0 = NEDGES-1;
    int sCur = csr_src[i0];
    const unsigned char* kb = KV + (size_t)sCur*384 + l*8;
    kv0 = *(const uint2*)(kb);
    kv1 = *(const uint2*)(kb+128);
    kv2 = *(const uint2*)(kb+256);
  }
  for(int base=0; base<deg; base+=4){
    const int inext = base + 4 + g;
    const int sNxt = csr_src[s0 + (inext<deg ? inext : 0)];
    const unsigned char* kbN = KV + (size_t)sNxt*384 + l*8;
    uint2 n0 = *(const uint2*)(kbN);
    uint2 n1 = *(const uint2*)(kbN+128);
    uint2 n2 = *(const uint2*)(kbN+256);

    const bool valid = (base + g < deg);
    f32x2 t0 = qlo[0]*fp8_lo(kv0.x) + qhi[0]*fp8_hi(kv0.x);
    f32x2 t1 = qlo[1]*fp8_lo(kv1.x) + qhi[1]*fp8_hi(kv1.x);
    f32x2 t2 = qlo[2]*fp8_lo(kv2.x) + qhi[2]*fp8_hi(kv2.x);
    float p0 = t0[0]+t0[1];
    float p1 = t1[0]+t1[1];
    float p2 = t2[0]+t2[1];
#pragma unroll
    for(int off=1; off<16; off<<=1){
      p0 += __shfl_xor(p0, off, 64);
      p1 += __shfl_xor(p1, off, 64);
      p2 += __shfl_xor(p2, off, 64);
    }
    float e0 = valid ? __expf(p0) : 0.f;
    float e1 = valid ? __expf(p1) : 0.f;
    float e2 = valid ? __expf(p2) : 0.f;
    d0 += e0; d1 += e1; d2 += e2;
    f32x2 e20 = {e0,e0}, e21 = {e1,e1}, e22 = {e2,e2};
    aLo[0] = fp8_lo(kv0.y)*e20 + aLo[0];
    aHi[0] = fp8_hi(kv0.y)*e20 + aHi[0];
    aLo[1] = fp8_lo(kv1.y)*e21 + aLo[1];
    aHi[1] = fp8_hi(kv1.y)*e21 + aHi[1];
    aLo[2] = fp8_lo(kv2.y)*e22 + aLo[2];
    aHi[2] = fp8_hi(kv2.y)*e22 + aHi[2];

    kv0=n0; kv1=n1; kv2=n2;
  }

  // cross-group reduction (groups hold disjoint edge subsets)
#pragma unroll
  for(int off=16; off<64; off<<=1){
#pragma unroll
    for(int h=0;h<3;++h){
      aLo[h][0]+=__shfl_xor(aLo[h][0],off,64); aLo[h][1]+=__shfl_xor(aLo[h][1],off,64);
      aHi[h][0]+=__shfl_xor(aHi[h][0],off,64); aHi[h][1]+=__shfl_xor(aHi[h][1],off,64);
    }
    d0+=__shfl_xor(d0,off,64); d1+=__shfl_xor(d1,off,64); d2+=__shfl_xor(d2,off,64);
  }
  const float dsum[3] = {d0,d1,d2};
  f32x2 oLo[3], oHi[3], rLo[3], rHi[3];
#pragma unroll
  for(int h=0;h<3;++h){
    float inv = 1.f/(dsum[h]+1e-16f);
    oLo[h] = aLo[h]*inv; oHi[h] = aHi[h]*inv;
    uint2 ur = *(const uint2*)(nr + 192 + 64*h);
    rLo[h] = bf2_to_f2(ur.x); rHi[h] = bf2_to_f2(ur.y);
  }

  f32x2 zz = {0,0};
#pragma unroll
  for(int h=0;h<3;++h){
    const float* wO = Wb + 64*h + 4*l;
    const float* wR = Wb + 192 + 64*h + 4*l;
    const float* wD = Wb + 384 + 64*h + 4*l;
    f32x2 woL = *(const f32x2*)(wO), woH = *(const f32x2*)(wO+2);
    f32x2 wrL = *(const f32x2*)(wR), wrH = *(const f32x2*)(wR+2);
    f32x2 wdL = *(const f32x2*)(wD), wdH = *(const f32x2*)(wD+2);
    zz = oLo[h]*woL + zz;
    zz = oHi[h]*woH + zz;
    zz = rLo[h]*wrL + zz;
    zz = rHi[h]*wrH + zz;
    zz = (oLo[h]-rLo[h])*wdL + zz;
    zz = (oHi[h]-rHi[h])*wdH + zz;
  }
  float z = zz[0]+zz[1];
#pragma unroll
  for(int off=1; off<16; off<<=1) z += __shfl_xor(z, off, 64);
  const float beta = 1.f/(1.f+__expf(-z));

  if(g==0){
#pragma unroll
    for(int h=0;h<3;++h){
      f32x2 hL = (rLo[h]-oLo[h])*beta + oLo[h];
      f32x2 hH = (rHi[h]-oHi[h])*beta + oHi[h];
      hL[0]=(hL[0]>0.f)?hL[0]:expm1f(hL[0]); hL[1]=(hL[1]>0.f)?hL[1]:expm1f(hL[1]);
      hH[0]=(hH[0]>0.f)?hH[0]:expm1f(hH[0]); hH[1]=(hH[1]>0.f)?hH[1]:expm1f(hH[1]);
      if(OUTBF){
        unsigned short* hb = HoutB + (size_t)n*HCDIM + 64*h + 4*l;
        ushort4 u;
        u.x=f2bf(hL[0]); u.y=f2bf(hL[1]); u.z=f2bf(hH[0]); u.w=f2bf(hH[1]);
        *(ushort4*)(hb) = u;
      } else {
        float* ho = HoutF + (size_t)n*HCDIM + 64*h + 4*l;
        float4 f; f.x=hL[0]; f.y=hL[1]; f.z=hH[0]; f.w=hH[1];
        *(float4*)(ho) = f;
      }
    }
  }
}

// ---------------- pooling + logits ----------------
// 32 nodes per block; batch sorted -> ~1 run/block
__global__ void pool_k(const float* __restrict__ H, const int* __restrict__ batch,
                       float* __restrict__ pooled, int* __restrict__ cnt, int N){
  const int t = threadIdx.x;       // 192 threads = channel
  int start = blockIdx.x*32;
  int end = min(start+32, N);
  if(start>=N) return;
  int cur = batch[start];
  float acc = 0.f;
  int run = 0;
  for(int nn=start; nn<end; ++nn){
    int g = batch[nn];
    if(g!=cur){
      atomicAdd(&pooled[(size_t)cur*HCDIM+t], acc);
      if(t==0) atomicAdd(&cnt[cur], run);
      acc=0.f; run=0; cur=g;
    }
    acc += H[(size_t)nn*HCDIM+t];
    run++;
  }
  atomicAdd(&pooled[(size_t)cur*HCDIM+t], acc);
  if(t==0) atomicAdd(&cnt[cur], run);
}

__global__ void logits_k(const float* __restrict__ pooled, const int* __restrict__ cnt,
                         const float* __restrict__ Wlin, const float* __restrict__ blin,
                         float* __restrict__ out){
  const int g = blockIdx.x;
  const int lane = threadIdx.x;    // 64 threads
  float c = fmaxf((float)cnt[g], 1.f);
  float s = 0.f;
#pragma unroll
  for(int j=0;j<3;++j){
    int col = j*64+lane;
    s += pooled[(size_t)g*HCDIM+col]/c * Wlin[col];
  }
  s = wave_sum(s);
  if(lane==0) out[g] = s + blin[0];
}

extern "C" void kernel_launch(void* const* d_in, const int* in_sizes, int n_in,
                              void* d_out, int out_size, void* d_ws, size_t ws_size,
                              hipStream_t stream)
{
  const int N=NNODES, E=NEDGES;
  const float* x     = (const float*)d_in[0];
  const int*   ei    = (const int*)d_in[1];
  const int*   batch = (const int*)d_in[2];
  const int* esrc = ei;
  const int* edst = ei + E;
  const float* Wq0=(const float*)d_in[3];  const float* bq0=(const float*)d_in[4];
  const float* Wk0=(const float*)d_in[5];  const float* bk0=(const float*)d_in[6];
  const float* Wv0=(const float*)d_in[7];  const float* bv0=(const float*)d_in[8];
  const float* Ws0=(const float*)d_in[9];  const float* bs0=(const float*)d_in[10];
  const float* Wb0=(const float*)d_in[11];
  const float* Wq1=(const float*)d_in[12]; const float* bq1=(const float*)d_in[13];
  const float* Wk1=(const float*)d_in[14]; const float* bk1=(const float*)d_in[15];
  const float* Wv1=(const float*)d_in[16]; const float* bv1=(const float*)d_in[17];
  const float* Ws1=(const float*)d_in[18]; const float* bs1=(const float*)d_in[19];
  const float* Wb1=(const float*)d_in[20];
  const float* Wlin=(const float*)d_in[21];
  const float* blin=(const float*)d_in[22];
  float* out = (float*)d_out;

  char* p = (char*)d_ws;
  auto alloc = [&](size_t bytes)->char*{
    char* q = p; p += (bytes+255)/256*256; return q;
  };
  unsigned short* Xb   = (unsigned short*)alloc((size_t)N*HCDIM*2);
  unsigned short* QR   = (unsigned short*)alloc((size_t)N*384*2);
  unsigned char*  KV   = (unsigned char*)alloc((size_t)N*384);
  float* H1            = (float*)alloc((size_t)N*HCDIM*4);
  unsigned short* Wt0  = (unsigned short*)alloc((size_t)QKVRW*DIM_IN*2);
  float* bcat0         = (float*)alloc(QKVRW*4);
  unsigned short* Wt1  = (unsigned short*)alloc((size_t)QKVRW*HCDIM*2);
  float* bcat1         = (float*)alloc(QKVRW*4);
  const size_t CSR_CHUNK = ((size_t)N*4+255)/256*256;
  int* counts  = (int*)alloc(CSR_CHUNK);
  int* row_ptr = (int*)alloc((size_t)(N+1)*4);
  int* csr     = (int*)alloc((size_t)E*4);
  int* bsum    = (int*)alloc(4096);
  float* pooled= (float*)alloc((size_t)NGRAPH*HCDIM*4); // pooled+cnt contiguous
  int* cnt     = (int*)alloc(256);

  const int NB = (N+255)/256;

  // ---- async zero-init (graph-capture legal) ----
  hipMemsetAsync(counts, 0, CSR_CHUNK, stream);
  hipMemsetAsync(pooled, 0, (size_t)NGRAPH*HCDIM*4 + 256, stream);

  // ---- fused prep (cast X, Wt0/bcat0, Wt1/bcat1, dst histogram) ----
  prep_all<<<CAST_BLKS + WT0_BLKS + WT1_BLKS + HIST_BLKS, 256, 0, stream>>>(
      x, Xb,
      Wq0,Wk0,Wv0,Ws0, bq0,bk0,bv0,bs0, Wt0, bcat0,
      Wq1,Wk1,Wv1,Ws1, bq1,bk1,bv1,bs1, Wt1, bcat1,
      edst, counts);

  // ---- CSR build ----
  scan_partial<<<NB,256,0,stream>>>(counts,bsum,N);
  scan_final<<<NB,256,0,stream>>>(counts,bsum,row_ptr,N);
  fill_k<<<(E+255)/256,256,0,stream>>>(esrc,edst,row_ptr,counts,csr,E);

  dim3 ggemm((N+127)/128, 6);
  // ---- layer 0 ----
  gemm_mfma<DIM_IN><<<ggemm,256,0,stream>>>(Xb,Wt0,bcat0,QR,KV,N);
  attn_kernel<true><<<(N+3)/4,256,0,stream>>>(QR,KV,row_ptr,csr,Wb0,nullptr,Xb,N);
  // ---- layer 1 ----
  gemm_mfma<HCDIM><<<ggemm,256,0,stream>>>(Xb,Wt1,bcat1,QR,KV,N);
  attn_kernel<false><<<(N+3)/4,256,0,stream>>>(QR,KV,row_ptr,csr,Wb1,H1,nullptr,N);

  // ---- pooling + logits ----
  pool_k<<<(N+31)/32,192,0,stream>>>(H1,batch,pooled,cnt,N);
  logits_k<<<NGRAPH,64,0,stream>>>(pooled,cnt,Wlin,blin,out);
}